// Round 1
// baseline (259.199 us; speedup 1.0000x reference)
//
#include <hip/hip_runtime.h>

#define N_NODES 500000
#define N_FEAT 125
#define HID 128
#define OUTD 64
#define N_GRAPHS 4096
#define TILE 128
#define NTILES ((N_NODES + TILE - 1) / TILE)
#define NBLOCKS 256
#define WPAD 136   /* padded row stride in bf16 elems (+8 keeps 16B align, breaks bank conflicts) */
#define OPAD 68    /* padded out row stride in floats */

typedef float f32x4 __attribute__((ext_vector_type(4)));
typedef short s16x8 __attribute__((ext_vector_type(8)));

// LDS layout (bytes)
#define OFF_W1 0
#define OFF_W2 (OFF_W1 + HID * WPAD * 2)          // 34816
#define OFF_W3 (OFF_W2 + HID * WPAD * 2)          // 69632
#define OFF_X  (OFF_W3 + OUTD * WPAD * 2)         // 87040
#define OFF_B  (OFF_X + HID * WPAD * 2)           // 121856
#define OFF_SB (OFF_B + (HID + HID + OUTD) * 4)   // 123136
#define LDS_BYTES (OFF_SB + TILE * 4)             // 123648

__device__ __forceinline__ unsigned short f2bf(float f) {
  union { float f; unsigned u; } v; v.f = f;
  unsigned r = v.u + 0x7FFFu + ((v.u >> 16) & 1u);  // RNE
  return (unsigned short)(r >> 16);
}

extern "C" __global__ void __launch_bounds__(256, 1)
gnn_main(const float* __restrict__ pos, const int* __restrict__ z,
         const int* __restrict__ batch, const float* __restrict__ emb,
         const float* __restrict__ W1, const float* __restrict__ b1,
         const float* __restrict__ W2, const float* __restrict__ b2,
         const float* __restrict__ W3, const float* __restrict__ b3,
         float* __restrict__ gsum, int* __restrict__ gcnt)
{
  extern __shared__ char lds[];
  unsigned short* w1t = (unsigned short*)(lds + OFF_W1);
  unsigned short* w2t = (unsigned short*)(lds + OFF_W2);
  unsigned short* w3t = (unsigned short*)(lds + OFF_W3);
  unsigned short* xb  = (unsigned short*)(lds + OFF_X);
  float* xout = (float*)(lds + OFF_X);              // aliases xb (used after last read)
  float* bias = (float*)(lds + OFF_B);
  int* sbatch = (int*)(lds + OFF_SB);

  const int t = threadIdx.x;

  // ---- stage weights once per block: bf16, transposed to [n][k], padded ----
  for (int i = t; i < HID * HID; i += 256) {
    int k = i >> 7, n = i & 127;                    // W row-major [k][n]; read coalesced
    w1t[n * WPAD + k] = f2bf(W1[i]);
    w2t[n * WPAD + k] = f2bf(W2[i]);
  }
  for (int i = t; i < HID * OUTD; i += 256) {
    int k = i >> 6, n = i & 63;
    w3t[n * WPAD + k] = f2bf(W3[i]);
  }
  if (t < HID) { bias[t] = b1[t]; bias[HID + t] = b2[t]; }
  if (t < OUTD) bias[2 * HID + t] = b3[t];
  __syncthreads();

  const int wave = t >> 6, lane = t & 63, quad = lane >> 4, l15 = lane & 15;

  for (int tile = blockIdx.x; tile < NTILES; tile += gridDim.x) {
    const int base = tile * TILE;
    const int nvalid = (N_NODES - base < TILE) ? (N_NODES - base) : TILE;

    if (t < TILE) sbatch[t] = (t < nvalid) ? batch[base + t] : -1;

    // ---- stage x tile: node = t>>1, 64 features per thread ----
    {
      const int node = t >> 1, half = t & 1, f0 = half * 64;
      if (node < nvalid) {
        const int gi = base + node;
        const float* er = emb + (long)z[gi] * N_FEAT;
        const float* pr = pos + (long)gi * 3;
        #pragma unroll
        for (int j = 0; j < 64; j += 2) {
          int f = f0 + j;
          float v0 = (f < 3) ? pr[f] : er[f - 3];
          float v1 = (f + 1 < 3) ? pr[f + 1] : er[f - 2];
          unsigned p = (unsigned)f2bf(v0) | ((unsigned)f2bf(v1) << 16);
          *(unsigned*)(xb + node * WPAD + f) = p;
        }
      } else {
        #pragma unroll
        for (int j = 0; j < 64; j += 2)
          *(unsigned*)(xb + node * WPAD + f0 + j) = 0u;
      }
    }
    __syncthreads();

    // ---- layers 1 & 2: [128x128] @ [128x128], relu, in-place LDS ----
    #pragma unroll 1
    for (int layer = 0; layer < 2; ++layer) {
      const unsigned short* wt = layer ? w2t : w1t;
      const float* bl = bias + layer * HID;
      const int rm = (wave >> 1) * 64, rn = (wave & 1) * 64;
      f32x4 acc[4][4] = {};
      #pragma unroll
      for (int k0 = 0; k0 < HID; k0 += 32) {
        s16x8 a[4], b[4];
        #pragma unroll
        for (int mi = 0; mi < 4; ++mi)
          a[mi] = *(const s16x8*)(xb + (rm + mi * 16 + l15) * WPAD + k0 + quad * 8);
        #pragma unroll
        for (int ni = 0; ni < 4; ++ni)
          b[ni] = *(const s16x8*)(wt + (rn + ni * 16 + l15) * WPAD + k0 + quad * 8);
        #pragma unroll
        for (int mi = 0; mi < 4; ++mi)
          #pragma unroll
          for (int ni = 0; ni < 4; ++ni)
            acc[mi][ni] = __builtin_amdgcn_mfma_f32_16x16x32_bf16(a[mi], b[ni], acc[mi][ni], 0, 0, 0);
      }
      __syncthreads();   // all waves finished reading xb -> safe to overwrite
      #pragma unroll
      for (int mi = 0; mi < 4; ++mi)
        #pragma unroll
        for (int ni = 0; ni < 4; ++ni)
          #pragma unroll
          for (int r = 0; r < 4; ++r) {
            int row = rm + mi * 16 + quad * 4 + r, col = rn + ni * 16 + l15;
            float v = acc[mi][ni][r] + bl[col];
            v = fmaxf(v, 0.f);
            xb[row * WPAD + col] = f2bf(v);
          }
      __syncthreads();
    }

    // ---- layer 3: [128x128] @ [128x64], +bias, fp32 to pooling buffer ----
    {
      const int rm = wave * 32;
      f32x4 acc[2][4] = {};
      #pragma unroll
      for (int k0 = 0; k0 < HID; k0 += 32) {
        s16x8 a[2], b[4];
        #pragma unroll
        for (int mi = 0; mi < 2; ++mi)
          a[mi] = *(const s16x8*)(xb + (rm + mi * 16 + l15) * WPAD + k0 + quad * 8);
        #pragma unroll
        for (int ni = 0; ni < 4; ++ni)
          b[ni] = *(const s16x8*)(w3t + (ni * 16 + l15) * WPAD + k0 + quad * 8);
        #pragma unroll
        for (int mi = 0; mi < 2; ++mi)
          #pragma unroll
          for (int ni = 0; ni < 4; ++ni)
            acc[mi][ni] = __builtin_amdgcn_mfma_f32_16x16x32_bf16(a[mi], b[ni], acc[mi][ni], 0, 0, 0);
      }
      __syncthreads();   // all waves finished reading xb -> safe to alias as xout
      #pragma unroll
      for (int mi = 0; mi < 2; ++mi)
        #pragma unroll
        for (int ni = 0; ni < 4; ++ni)
          #pragma unroll
          for (int r = 0; r < 4; ++r) {
            int row = rm + mi * 16 + quad * 4 + r, col = ni * 16 + l15;
            xout[row * OPAD + col] = acc[mi][ni][r] + bias[2 * HID + col];
          }
      __syncthreads();
    }

    // ---- segment-sum pooling: batch is sorted -> run-scan, 1 atomic per run ----
    {
      const int o = t & 63, q = t >> 6;
      const int ns = q * 32;
      int cur = sbatch[ns];
      float run = 0.f; int rc = 0;
      #pragma unroll 1
      for (int n = ns; n < ns + 32; ++n) {
        int b = sbatch[n];
        if (b != cur) {
          if (cur >= 0) {
            atomicAdd(&gsum[cur * OUTD + o], run);
            if (o == 0) atomicAdd(&gcnt[cur], rc);
          }
          run = 0.f; rc = 0; cur = b;
        }
        if (b >= 0) { run += xout[n * OPAD + o]; rc++; }
      }
      if (cur >= 0) {
        atomicAdd(&gsum[cur * OUTD + o], run);
        if (o == 0) atomicAdd(&gcnt[cur], rc);
      }
    }
    __syncthreads();   // before next tile overwrites xb/sbatch
  }
}

extern "C" __global__ void gnn_finalize(const float* __restrict__ gsum,
                                        const int* __restrict__ gcnt,
                                        float* __restrict__ out)
{
  int i = blockIdx.x * 256 + threadIdx.x;
  if (i < N_GRAPHS * OUTD) {
    int g = i >> 6;
    int c = gcnt[g]; if (c < 1) c = 1;
    out[i] = gsum[i] / (float)c;
  }
}

extern "C" void kernel_launch(void* const* d_in, const int* in_sizes, int n_in,
                              void* d_out, int out_size, void* d_ws, size_t ws_size,
                              hipStream_t stream) {
  const float* pos  = (const float*)d_in[0];
  const int*   z    = (const int*)d_in[1];
  const int*   batch= (const int*)d_in[2];
  const float* emb  = (const float*)d_in[3];
  const float* W1   = (const float*)d_in[4];
  const float* b1   = (const float*)d_in[5];
  const float* W2   = (const float*)d_in[6];
  const float* b2   = (const float*)d_in[7];
  const float* W3   = (const float*)d_in[8];
  const float* b3   = (const float*)d_in[9];

  float* gsum = (float*)d_ws;
  int*   gcnt = (int*)((char*)d_ws + (size_t)N_GRAPHS * OUTD * 4);
  size_t zbytes = (size_t)N_GRAPHS * OUTD * 4 + (size_t)N_GRAPHS * 4;
  hipMemsetAsync(d_ws, 0, zbytes, stream);

  // allow >64KB dynamic LDS (ignore result; AMD typically allows up to HW max)
  hipFuncSetAttribute((const void*)gnn_main,
                      hipFuncAttributeMaxDynamicSharedMemorySize, LDS_BYTES);

  hipLaunchKernelGGL(gnn_main, dim3(NBLOCKS), dim3(256), LDS_BYTES, stream,
                     pos, z, batch, emb, W1, b1, W2, b2, W3, b3, gsum, gcnt);
  hipLaunchKernelGGL(gnn_finalize, dim3((N_GRAPHS * OUTD + 255) / 256), dim3(256), 0, stream,
                     gsum, gcnt, (float*)d_out);
}

// Round 3
// 182.999 us; speedup vs baseline: 1.4164x; 1.4164x over previous
//
#include <hip/hip_runtime.h>

#define N_NODES 500000
#define N_FEAT 125
#define HID 128
#define OUTD 64
#define N_GRAPHS 4096
#define WTILE 32
#define NTILES32 ((N_NODES + WTILE - 1) / WTILE)   /* 15625 (exact: 32*15625) */
#define NBLOCKS 256
#define NWAVES 8
#define WPAD 136    /* bf16 row stride: 16B-aligned, 68 dwords == 4 mod 32 banks */
#define OPADF 68    /* f32 row stride for pooling buffer (aliases scratch) */

typedef float f32x4 __attribute__((ext_vector_type(4)));
typedef short s16x8 __attribute__((ext_vector_type(8)));

// LDS layout (bytes)
#define OFF_W1 0
#define OFF_W2 (OFF_W1 + HID * WPAD * 2)           // 34816
#define OFF_W3 (OFF_W2 + HID * WPAD * 2)           // 69632
#define OFF_B  (OFF_W3 + OUTD * WPAD * 2)          // 87040
#define OFF_SCR (OFF_B + (HID + HID + OUTD) * 4)   // 88320
#define SCR_BYTES (WTILE * WPAD * 2)               // 8704 per wave (== 32*68*4 as f32)
#define OFF_IDS (OFF_SCR + NWAVES * SCR_BYTES)     // 157952
#define LDS_BYTES (OFF_IDS + NWAVES * WTILE * 4)   // 158976 (<= 163840)

__device__ __forceinline__ unsigned short f2bf(float f) {
  union { float f; unsigned u; } v; v.f = f;
  unsigned r = v.u + 0x7FFFu + ((v.u >> 16) & 1u);  // RNE
  return (unsigned short)(r >> 16);
}

// Wave-local LDS ordering: DS pipe executes a wave's LDS ops in order; this
// fence only stops the COMPILER from reordering reads above prior writes.
__device__ __forceinline__ void wavefence() {
  __builtin_amdgcn_sched_barrier(0);
  __builtin_amdgcn_wave_barrier();
  __builtin_amdgcn_sched_barrier(0);
}

extern "C" __global__ void __launch_bounds__(512, 2)
gnn_main(const float* __restrict__ pos, const int* __restrict__ z,
         const int* __restrict__ batch, const float* __restrict__ emb,
         const float* __restrict__ W1, const float* __restrict__ b1,
         const float* __restrict__ W2, const float* __restrict__ b2,
         const float* __restrict__ W3, const float* __restrict__ b3,
         float* __restrict__ gsum, int* __restrict__ gcnt)
{
  extern __shared__ char lds[];
  unsigned short* w1t = (unsigned short*)(lds + OFF_W1);
  unsigned short* w2t = (unsigned short*)(lds + OFF_W2);
  unsigned short* w3t = (unsigned short*)(lds + OFF_W3);
  float* bias = (float*)(lds + OFF_B);

  const int t = threadIdx.x;

  // ---- stage weights once per block: bf16, [n][k] transposed, padded ----
  for (int i = t; i < HID * HID; i += 512) {
    int k = i >> 7, n = i & 127;                    // W row-major [k][n]
    w1t[n * WPAD + k] = f2bf(W1[i]);
    w2t[n * WPAD + k] = f2bf(W2[i]);
  }
  for (int i = t; i < HID * OUTD; i += 512) {
    int k = i >> 6, n = i & 63;
    w3t[n * WPAD + k] = f2bf(W3[i]);
  }
  if (t < HID) { bias[t] = b1[t]; bias[HID + t] = b2[t]; }
  if (t < OUTD) bias[2 * HID + t] = b3[t];
  __syncthreads();   // the ONLY block-wide barrier

  const int wave = t >> 6, lane = t & 63, quad = lane >> 4, l15 = lane & 15;
  unsigned short* xs = (unsigned short*)(lds + OFF_SCR + wave * SCR_BYTES);
  float* xo = (float*)xs;                            // aliases xs (order-safe)
  int* ids = (int*)(lds + OFF_IDS) + wave * WTILE;

  const int gwave = blockIdx.x * NWAVES + wave;

  for (int tile = gwave; tile < NTILES32; tile += NBLOCKS * NWAVES) {
    const int base = tile * WTILE;

    if (lane < WTILE) {
      int n = base + lane;
      ids[lane] = (n < N_NODES) ? batch[n] : -1;
    }

    // ---- gather 32 nodes directly into A-fragments (no LDS, no barrier) ----
    s16x8 a[2][4];
    #pragma unroll
    for (int m = 0; m < 2; ++m) {
      const int node = base + m * 16 + l15;
      const bool valid = node < N_NODES;
      const int zi = valid ? z[node] : 0;
      const float* er = emb + (long)zi * N_FEAT;
      #pragma unroll
      for (int k = 0; k < 4; ++k) {
        const int f0 = k * 32 + quad * 8;
        s16x8 frag;
        #pragma unroll
        for (int j = 0; j < 8; ++j) {
          const int f = f0 + j;
          float v = 0.f;
          if (valid) v = (f < 3) ? pos[(long)node * 3 + f] : er[f - 3];
          frag[j] = (short)f2bf(v);
        }
        a[m][k] = frag;
      }
    }

    // ---- layer 1: 32x128 @ 128x128 ----
    f32x4 acc[2][8] = {};
    #pragma unroll
    for (int n = 0; n < 8; ++n)
      #pragma unroll
      for (int k = 0; k < 4; ++k) {
        s16x8 b = *(const s16x8*)(w1t + (n * 16 + l15) * WPAD + k * 32 + quad * 8);
        acc[0][n] = __builtin_amdgcn_mfma_f32_16x16x32_bf16(a[0][k], b, acc[0][n], 0, 0, 0);
        acc[1][n] = __builtin_amdgcn_mfma_f32_16x16x32_bf16(a[1][k], b, acc[1][n], 0, 0, 0);
      }

    // epilogue 1: bias+relu -> bf16 scratch (C-layout -> row-major)
    #pragma unroll
    for (int m = 0; m < 2; ++m)
      #pragma unroll
      for (int n = 0; n < 8; ++n)
        #pragma unroll
        for (int r = 0; r < 4; ++r) {
          int row = m * 16 + quad * 4 + r, col = n * 16 + l15;
          float v = acc[m][n][r] + bias[col];
          xs[row * WPAD + col] = f2bf(fmaxf(v, 0.f));
        }
    wavefence();
    #pragma unroll
    for (int m = 0; m < 2; ++m)
      #pragma unroll
      for (int k = 0; k < 4; ++k)
        a[m][k] = *(const s16x8*)(xs + (m * 16 + l15) * WPAD + k * 32 + quad * 8);
    wavefence();

    // ---- layer 2: 32x128 @ 128x128 ----
    #pragma unroll
    for (int m = 0; m < 2; ++m)
      #pragma unroll
      for (int n = 0; n < 8; ++n) acc[m][n] = (f32x4){0.f, 0.f, 0.f, 0.f};
    #pragma unroll
    for (int n = 0; n < 8; ++n)
      #pragma unroll
      for (int k = 0; k < 4; ++k) {
        s16x8 b = *(const s16x8*)(w2t + (n * 16 + l15) * WPAD + k * 32 + quad * 8);
        acc[0][n] = __builtin_amdgcn_mfma_f32_16x16x32_bf16(a[0][k], b, acc[0][n], 0, 0, 0);
        acc[1][n] = __builtin_amdgcn_mfma_f32_16x16x32_bf16(a[1][k], b, acc[1][n], 0, 0, 0);
      }
    #pragma unroll
    for (int m = 0; m < 2; ++m)
      #pragma unroll
      for (int n = 0; n < 8; ++n)
        #pragma unroll
        for (int r = 0; r < 4; ++r) {
          int row = m * 16 + quad * 4 + r, col = n * 16 + l15;
          float v = acc[m][n][r] + bias[HID + col];
          xs[row * WPAD + col] = f2bf(fmaxf(v, 0.f));
        }
    wavefence();
    #pragma unroll
    for (int m = 0; m < 2; ++m)
      #pragma unroll
      for (int k = 0; k < 4; ++k)
        a[m][k] = *(const s16x8*)(xs + (m * 16 + l15) * WPAD + k * 32 + quad * 8);
    wavefence();

    // ---- layer 3: 32x128 @ 128x64, +bias, f32 -> pooling buffer ----
    f32x4 acc3[2][4] = {};
    #pragma unroll
    for (int n = 0; n < 4; ++n)
      #pragma unroll
      for (int k = 0; k < 4; ++k) {
        s16x8 b = *(const s16x8*)(w3t + (n * 16 + l15) * WPAD + k * 32 + quad * 8);
        acc3[0][n] = __builtin_amdgcn_mfma_f32_16x16x32_bf16(a[0][k], b, acc3[0][n], 0, 0, 0);
        acc3[1][n] = __builtin_amdgcn_mfma_f32_16x16x32_bf16(a[1][k], b, acc3[1][n], 0, 0, 0);
      }
    #pragma unroll
    for (int m = 0; m < 2; ++m)
      #pragma unroll
      for (int n = 0; n < 4; ++n)
        #pragma unroll
        for (int r = 0; r < 4; ++r) {
          int row = m * 16 + quad * 4 + r, col = n * 16 + l15;
          xo[row * OPADF + col] = acc3[m][n][r] + bias[2 * HID + col];
        }
    wavefence();

    // ---- pool: sorted batch -> run-scan; ids are wave-uniform -> no divergence
    {
      const int o = lane;   // output dim 0..63
      int cur = ids[0];
      float run = 0.f; int rc = 0;
      #pragma unroll 1
      for (int n = 0; n < WTILE; ++n) {
        int bb = ids[n];
        if (bb != cur) {
          if (cur >= 0) {
            atomicAdd(&gsum[cur * OUTD + o], run);
            if (o == 0) atomicAdd(&gcnt[cur], rc);
          }
          run = 0.f; rc = 0; cur = bb;
        }
        if (bb >= 0) { run += xo[n * OPADF + o]; rc++; }
      }
      if (cur >= 0) {
        atomicAdd(&gsum[cur * OUTD + o], run);
        if (o == 0) atomicAdd(&gcnt[cur], rc);
      }
    }
    wavefence();   // next tile overwrites xs/ids (same wave -> fence suffices)
  }
}

extern "C" __global__ void gnn_finalize(const float* __restrict__ gsum,
                                        const int* __restrict__ gcnt,
                                        float* __restrict__ out)
{
  int i = blockIdx.x * 256 + threadIdx.x;
  if (i < N_GRAPHS * OUTD) {
    int g = i >> 6;
    int c = gcnt[g]; if (c < 1) c = 1;
    out[i] = gsum[i] / (float)c;
  }
}

extern "C" void kernel_launch(void* const* d_in, const int* in_sizes, int n_in,
                              void* d_out, int out_size, void* d_ws, size_t ws_size,
                              hipStream_t stream) {
  const float* pos  = (const float*)d_in[0];
  const int*   z    = (const int*)d_in[1];
  const int*   batch= (const int*)d_in[2];
  const float* emb  = (const float*)d_in[3];
  const float* W1   = (const float*)d_in[4];
  const float* b1   = (const float*)d_in[5];
  const float* W2   = (const float*)d_in[6];
  const float* b2   = (const float*)d_in[7];
  const float* W3   = (const float*)d_in[8];
  const float* b3   = (const float*)d_in[9];

  float* gsum = (float*)d_ws;
  int*   gcnt = (int*)((char*)d_ws + (size_t)N_GRAPHS * OUTD * 4);
  size_t zbytes = (size_t)N_GRAPHS * OUTD * 4 + (size_t)N_GRAPHS * 4;
  hipMemsetAsync(d_ws, 0, zbytes, stream);

  hipFuncSetAttribute((const void*)gnn_main,
                      hipFuncAttributeMaxDynamicSharedMemorySize, LDS_BYTES);

  hipLaunchKernelGGL(gnn_main, dim3(NBLOCKS), dim3(512), LDS_BYTES, stream,
                     pos, z, batch, emb, W1, b1, W2, b2, W3, b3, gsum, gcnt);
  hipLaunchKernelGGL(gnn_finalize, dim3((N_GRAPHS * OUTD + 255) / 256), dim3(256), 0, stream,
                     gsum, gcnt, (float*)d_out);
}

// Round 4
// 148.188 us; speedup vs baseline: 1.7491x; 1.2349x over previous
//
#include <hip/hip_runtime.h>
#include <hip/hip_bf16.h>

#define N_NODES 500000
#define N_FEAT 125
#define HID 128
#define OUTD 64
#define N_GRAPHS 4096
#define N_TYPES 100
#define WTILE 32
#define NTILES32 (N_NODES / WTILE)        /* 15625 exact — no tail handling */
#define NBLOCKS 256
#define NWAVES 8
#define WPAD 136    /* bf16 row stride: 16B-aligned; 68 dwords == 4 mod 32 banks */
#define OPADF 68    /* f32 row stride, aliases bf16 scratch exactly (32*68*4 == 32*136*2) */

typedef float f32x4 __attribute__((ext_vector_type(4)));
typedef short s16x8 __attribute__((ext_vector_type(8)));

// LDS layout (bytes)
#define OFF_T 0
#define SZ_T (N_TYPES * WPAD * 2)                  // 27200
#define OFF_W2 (OFF_T + SZ_T)
#define OFF_W3 (OFF_W2 + HID * WPAD * 2)           // +34816
#define OFF_B2 (OFF_W3 + OUTD * WPAD * 2)          // +17408
#define OFF_SCR (OFF_B2 + HID * 4)                 // +512  -> 79936
#define SCR_BYTES (WTILE * WPAD * 2)               // 8704/wave
#define OFF_IDS (OFF_SCR + NWAVES * SCR_BYTES)     // 149568
#define LDS_BYTES (OFF_IDS + NWAVES * WTILE * 4)   // 150592 (<= 163840)

// ws layout (bytes)
#define WS_GSUM 0
#define WS_GCNT ((size_t)N_GRAPHS * OUTD * 4)      // 1048576
#define WS_T    (WS_GCNT + (size_t)N_GRAPHS * 4)   // 1064960
#define WS_ZERO WS_T                               // bytes to memset (gsum+gcnt)

__device__ __forceinline__ unsigned short f2bf(float f) {
  union { float f; unsigned u; } v; v.f = f;
  unsigned r = v.u + 0x7FFFu + ((v.u >> 16) & 1u);  // RNE
  return (unsigned short)(r >> 16);
}
__device__ __forceinline__ float bf2f(unsigned short u) {
  union { unsigned u; float f; } v; v.u = ((unsigned)u) << 16;
  return v.f;
}
__device__ __forceinline__ unsigned pk2bf(float a, float b) {
  __hip_bfloat162 h = __float22bfloat162_rn(float2{a, b});   // .x -> low 16, .y -> high 16
  union { __hip_bfloat162 h; unsigned u; } v; v.h = h;
  return v.u;
}

// Wave-local LDS ordering fence (DS pipe is in-order per wave; this stops the
// compiler from reordering may-alias LDS ops). Proven correct in R3.
__device__ __forceinline__ void wavefence() {
  __builtin_amdgcn_sched_barrier(0);
  __builtin_amdgcn_wave_barrier();
  __builtin_amdgcn_sched_barrier(0);
}

// ---- pre-pass: T[100][128] = emb @ W1[3:,:] + b1  (fp32 math, bf16 store) ----
extern "C" __global__ void gnn_prep(const float* __restrict__ emb,
                                    const float* __restrict__ W1,
                                    const float* __restrict__ b1,
                                    unsigned short* __restrict__ Tg)
{
  const int g = blockIdx.x, j = threadIdx.x;     // 100 blocks x 128 threads
  float acc = b1[j];
  const float* er = emb + g * N_FEAT;
  for (int k = 0; k < N_FEAT; ++k)
    acc = fmaf(er[k], W1[(3 + k) * HID + j], acc);   // W1 read coalesced over j
  Tg[g * HID + j] = f2bf(acc);
}

extern "C" __global__ void __launch_bounds__(512, 2)
gnn_main(const float* __restrict__ pos, const int* __restrict__ z,
         const int* __restrict__ batch, const unsigned short* __restrict__ Tg,
         const float* __restrict__ W1, const float* __restrict__ W2,
         const float* __restrict__ b2, const float* __restrict__ W3,
         float* __restrict__ gsum, int* __restrict__ gcnt)
{
  extern __shared__ char lds[];
  unsigned short* Tl  = (unsigned short*)(lds + OFF_T);
  unsigned short* w2t = (unsigned short*)(lds + OFF_W2);
  unsigned short* w3t = (unsigned short*)(lds + OFF_W3);
  float* bias2 = (float*)(lds + OFF_B2);

  const int t = threadIdx.x;

  // ---- stage once per block ----
  for (int i = t; i < N_TYPES * HID; i += 512) {   // T: bf16, padded rows
    int g = i >> 7, f = i & 127;
    Tl[g * WPAD + f] = Tg[i];
  }
  for (int i = t; i < HID * HID; i += 512) {       // W2^T [n][k] bf16
    int k = i >> 7, n = i & 127;
    w2t[n * WPAD + k] = f2bf(W2[i]);
  }
  for (int i = t; i < HID * OUTD; i += 512) {      // W3^T [n][k] bf16
    int k = i >> 6, n = i & 63;
    w3t[n * WPAD + k] = f2bf(W3[i]);
  }
  if (t < HID) bias2[t] = b2[t];

  const int wave = t >> 6, lane = t & 63, quad = lane >> 4, l15 = lane & 15;
  unsigned short* xs = (unsigned short*)(lds + OFF_SCR + wave * SCR_BYTES);
  float* xo = (float*)xs;                          // aliases xs (wave-order-safe)
  int* ids = (int*)(lds + OFF_IDS) + wave * WTILE;

  // ---- per-lane W1 pos-row coefficients, fp32, tile-invariant (96 VGPRs) ----
  float w1r[3][4][8];
  #pragma unroll
  for (int c = 0; c < 3; ++c)
    #pragma unroll
    for (int k = 0; k < 4; ++k)
      #pragma unroll
      for (int j = 0; j < 8; ++j)
        w1r[c][k][j] = W1[c * HID + k * 32 + quad * 8 + j];

  __syncthreads();   // the ONLY block-wide barrier

  const int gwave = blockIdx.x * NWAVES + wave;

  for (int tile = gwave; tile < NTILES32; tile += NBLOCKS * NWAVES) {
    const int base = tile * WTILE;

    if (lane < WTILE) ids[lane] = batch[base + lane];

    // ---- layer 1 in VALU, directly into MFMA B-fragments (x^T operand) ----
    // h1[node][f] = relu(T[z][f] + px*W1r0[f] + py*W1r1[f] + pz*W1r2[f])
    s16x8 a[2][4];
    #pragma unroll
    for (int m = 0; m < 2; ++m) {
      const int node = base + m * 16 + l15;        // always < N_NODES (exact tiles)
      const int zi = z[node];
      const float px = pos[node * 3], py = pos[node * 3 + 1], pz = pos[node * 3 + 2];
      const unsigned short* Tr = Tl + zi * WPAD;
      #pragma unroll
      for (int k = 0; k < 4; ++k) {
        s16x8 tf = *(const s16x8*)(Tr + k * 32 + quad * 8);
        s16x8 fr;
        #pragma unroll
        for (int j = 0; j < 8; j += 2) {
          float v0 = bf2f((unsigned short)tf[j])
                   + px * w1r[0][k][j] + py * w1r[1][k][j] + pz * w1r[2][k][j];
          float v1 = bf2f((unsigned short)tf[j + 1])
                   + px * w1r[0][k][j + 1] + py * w1r[1][k][j + 1] + pz * w1r[2][k][j + 1];
          ((unsigned*)&fr)[j >> 1] = pk2bf(fmaxf(v0, 0.f), fmaxf(v1, 0.f));
        }
        a[m][k] = fr;
      }
    }

    // ---- layer 2: D = W2^T(A) x h1^T(B) -> C: row=out-feature, col=node ----
    f32x4 acc[8][2] = {};
    #pragma unroll
    for (int oi = 0; oi < 8; ++oi)
      #pragma unroll
      for (int k = 0; k < 4; ++k) {
        s16x8 w = *(const s16x8*)(w2t + (oi * 16 + l15) * WPAD + k * 32 + quad * 8);
        acc[oi][0] = __builtin_amdgcn_mfma_f32_16x16x32_bf16(w, a[0][k], acc[oi][0], 0, 0, 0);
        acc[oi][1] = __builtin_amdgcn_mfma_f32_16x16x32_bf16(w, a[1][k], acc[oi][1], 0, 0, 0);
      }
    // epilogue 2: 4 consecutive features per lane -> packed b64 writes
    #pragma unroll
    for (int oi = 0; oi < 8; ++oi) {
      const int f0 = oi * 16 + quad * 4;
      f32x4 bv = *(const f32x4*)(bias2 + f0);
      #pragma unroll
      for (int m = 0; m < 2; ++m) {
        unsigned lo = pk2bf(fmaxf(acc[oi][m][0] + bv[0], 0.f),
                            fmaxf(acc[oi][m][1] + bv[1], 0.f));
        unsigned hi = pk2bf(fmaxf(acc[oi][m][2] + bv[2], 0.f),
                            fmaxf(acc[oi][m][3] + bv[3], 0.f));
        *(uint2*)(xs + (m * 16 + l15) * WPAD + f0) = uint2{lo, hi};
      }
    }
    wavefence();
    #pragma unroll
    for (int m = 0; m < 2; ++m)
      #pragma unroll
      for (int k = 0; k < 4; ++k)
        a[m][k] = *(const s16x8*)(xs + (m * 16 + l15) * WPAD + k * 32 + quad * 8);
    wavefence();

    // ---- layer 3: D = W3^T x h2^T -> row=out-dim, col=node; b3 folded into finalize
    f32x4 acc3[4][2] = {};
    #pragma unroll
    for (int oi = 0; oi < 4; ++oi)
      #pragma unroll
      for (int k = 0; k < 4; ++k) {
        s16x8 w = *(const s16x8*)(w3t + (oi * 16 + l15) * WPAD + k * 32 + quad * 8);
        acc3[oi][0] = __builtin_amdgcn_mfma_f32_16x16x32_bf16(w, a[0][k], acc3[oi][0], 0, 0, 0);
        acc3[oi][1] = __builtin_amdgcn_mfma_f32_16x16x32_bf16(w, a[1][k], acc3[oi][1], 0, 0, 0);
      }
    #pragma unroll
    for (int oi = 0; oi < 4; ++oi)
      #pragma unroll
      for (int m = 0; m < 2; ++m)
        *(f32x4*)(xo + (m * 16 + l15) * OPADF + oi * 16 + quad * 4) = acc3[oi][m];
    wavefence();

    // ---- pool: sorted batch -> run-scan; ids wave-uniform -> uniform branches
    {
      const int o = lane;                          // output dim 0..63
      int cur = ids[0];
      float run = 0.f; int rc = 0;
      #pragma unroll 1
      for (int n = 0; n < WTILE; ++n) {
        int bb = ids[n];
        if (bb != cur) {
          atomicAdd(&gsum[cur * OUTD + o], run);
          if (o == 0) atomicAdd(&gcnt[cur], rc);
          run = 0.f; rc = 0; cur = bb;
        }
        run += xo[n * OPADF + o]; rc++;
      }
      atomicAdd(&gsum[cur * OUTD + o], run);
      if (o == 0) atomicAdd(&gcnt[cur], rc);
    }
    wavefence();   // next tile reuses xs/ids (same wave)
  }
}

extern "C" __global__ void gnn_finalize(const float* __restrict__ gsum,
                                        const int* __restrict__ gcnt,
                                        const float* __restrict__ b3,
                                        float* __restrict__ out)
{
  int i = blockIdx.x * 256 + threadIdx.x;
  if (i < N_GRAPHS * OUTD) {
    int g = i >> 6, o = i & 63;
    int c = gcnt[g];
    out[i] = (c > 0) ? (gsum[i] / (float)c + b3[o]) : 0.f;
  }
}

extern "C" void kernel_launch(void* const* d_in, const int* in_sizes, int n_in,
                              void* d_out, int out_size, void* d_ws, size_t ws_size,
                              hipStream_t stream) {
  const float* pos  = (const float*)d_in[0];
  const int*   z    = (const int*)d_in[1];
  const int*   batch= (const int*)d_in[2];
  const float* emb  = (const float*)d_in[3];
  const float* W1   = (const float*)d_in[4];
  const float* b1   = (const float*)d_in[5];
  const float* W2   = (const float*)d_in[6];
  const float* b2   = (const float*)d_in[7];
  const float* W3   = (const float*)d_in[8];
  const float* b3   = (const float*)d_in[9];

  float* gsum = (float*)d_ws;
  int*   gcnt = (int*)((char*)d_ws + WS_GCNT);
  unsigned short* Tg = (unsigned short*)((char*)d_ws + WS_T);

  hipMemsetAsync(d_ws, 0, WS_ZERO, stream);

  hipLaunchKernelGGL(gnn_prep, dim3(N_TYPES), dim3(HID), 0, stream, emb, W1, b1, Tg);

  hipFuncSetAttribute((const void*)gnn_main,
                      hipFuncAttributeMaxDynamicSharedMemorySize, LDS_BYTES);
  hipLaunchKernelGGL(gnn_main, dim3(NBLOCKS), dim3(512), LDS_BYTES, stream,
                     pos, z, batch, Tg, W1, W2, b2, W3, gsum, gcnt);
  hipLaunchKernelGGL(gnn_finalize, dim3((N_GRAPHS * OUTD + 255) / 256), dim3(256), 0, stream,
                     gsum, gcnt, b3, (float*)d_out);
}